// Round 3
// baseline (2747.363 us; speedup 1.0000x reference)
//
#include <hip/hip_runtime.h>
#include <stdint.h>

#define NB 8
#define NC 19
#define NH 512
#define NW 512
#define HW (NH * NW)        // 262144
#define CHW (NC * HW)       // 4980736
#define NPIX (NB * HW)      // 2097152
#define NSAMP 32

struct SampleKeys { uint32_t k0[NSAMP]; uint32_t k1[NSAMP]; };

// Threefry-2x32, 20 rounds, exactly JAX's threefry2x32 primitive.
__host__ __device__ inline void tf2x32(uint32_t k0, uint32_t k1,
                                       uint32_t c0, uint32_t c1,
                                       uint32_t &o0, uint32_t &o1) {
  const uint32_t ks2 = k0 ^ k1 ^ 0x1BD11BDAu;
  uint32_t x0 = c0 + k0;
  uint32_t x1 = c1 + k1;
#define TFR(r) do { x0 += x1; x1 = (x1 << (r)) | (x1 >> (32 - (r))); x1 ^= x0; } while (0)
  TFR(13); TFR(15); TFR(26); TFR(6);
  x0 += k1; x1 += ks2 + 1u;
  TFR(17); TFR(29); TFR(16); TFR(24);
  x0 += ks2; x1 += k0 + 2u;
  TFR(13); TFR(15); TFR(26); TFR(6);
  x0 += k0; x1 += k1 + 3u;
  TFR(17); TFR(29); TFR(16); TFR(24);
  x0 += k1; x1 += ks2 + 4u;
  TFR(13); TFR(15); TFR(26); TFR(6);
  x0 += ks2; x1 += k0 + 5u;
#undef TFR
  o0 = x0; o1 = x1;
}

// bits -> uniform in [nextafter(-1,0), 1) -> sqrt(2)*erfinv(u), XLA Giles poly.
// RNG math frozen (stream verified round 1-2, absmax 2^-9, 9x under threshold).
__device__ __forceinline__ float normal_from_bits(uint32_t bits) {
  const float LO = -0.99999994039535522461f;  // nextafter(-1.f, 0.f)
  float f = __uint_as_float((bits >> 9) | 0x3F800000u) - 1.0f;  // [0,1)
  float u = fmaf(f, 2.0f, LO);
  u = fmaxf(u, LO);
  float w = -__logf(fmaf(-u, u, 1.0f));  // -log(1-u^2)
  // low branch (w < 5) — always computed
  float wl = w - 2.5f;
  float p = 2.81022636e-08f;
  p = fmaf(p, wl, 3.43273939e-07f);
  p = fmaf(p, wl, -3.5233877e-06f);
  p = fmaf(p, wl, -4.39150654e-06f);
  p = fmaf(p, wl, 0.00021858087f);
  p = fmaf(p, wl, -0.00125372503f);
  p = fmaf(p, wl, -0.00417768164f);
  p = fmaf(p, wl, 0.246640727f);
  p = fmaf(p, wl, 1.50140941f);
  if (__builtin_expect(__any(w >= 5.0f), 0)) {
    float wh = sqrtf(w) - 3.0f;
    float q = -0.000200214257f;
    q = fmaf(q, wh, 0.000100950558f);
    q = fmaf(q, wh, 0.00134934322f);
    q = fmaf(q, wh, -0.00367342844f);
    q = fmaf(q, wh, 0.00573950773f);
    q = fmaf(q, wh, -0.0076224613f);
    q = fmaf(q, wh, 0.00943887047f);
    q = fmaf(q, wh, 1.00167406f);
    q = fmaf(q, wh, 2.83297682f);
    p = (w < 5.0f) ? p : q;
  }
  return 1.41421356237f * (p * u);
}

// waves_per_eu(3,4): register budget 512/3 ~= 170 VGPRs. Live state
// (lg/sd/acc/ts = 76 floats + temps) needs ~120-140 regs; the default
// heuristic (and launch_bounds(256,4)) chased 8-waves occupancy by
// spilling down to 64 regs -> 112 MB of scratch writes/dispatch (round 2).
__global__ __launch_bounds__(256)
__attribute__((amdgpu_waves_per_eu(3, 4)))
void mcsm(const float* __restrict__ logits,
          const float* __restrict__ stdv,
          float* __restrict__ out,
          SampleKeys keys) {
  uint32_t p = blockIdx.x * 256u + threadIdx.x;  // pixel id in [0, NPIX)
  uint32_t b = p >> 18;                          // / HW
  uint32_t rem = p & (HW - 1u);                  // h*W + w
  uint32_t base = b * (uint32_t)CHW + rem;       // flat index at c=0

  float lg[NC], sd[NC], acc[NC];
#pragma unroll
  for (int c = 0; c < NC; ++c) {
    lg[c] = logits[base + (uint32_t)(c * HW)];
    sd[c] = stdv[base + (uint32_t)(c * HW)];
    acc[c] = 0.0f;
  }

#pragma unroll 1
  for (int s = 0; s < NSAMP; ++s) {
    uint32_t k0 = keys.k0[s], k1 = keys.k1[s];
    float ts[NC];
    float sum = 0.0f;
    // No max-subtraction: |x| <= ~12, exp stays comfortably in f32 range.
#pragma unroll
    for (int c = 0; c < NC; ++c) {
      uint32_t o0, o1;
      tf2x32(k0, k1, 0u, base + (uint32_t)(c * HW), o0, o1);
      float e = normal_from_bits(o0 ^ o1);   // partitionable: xor of halves
      float x = fmaf(e, sd[c], lg[c]);       // logits + eps*std
      float t = __expf(x);
      ts[c] = t;
      sum += t;
    }
    float rs = __builtin_amdgcn_rcpf(sum);
#pragma unroll
    for (int c = 0; c < NC; ++c) acc[c] = fmaf(ts[c], rs, acc[c]);
  }

#pragma unroll
  for (int c = 0; c < NC; ++c)
    out[base + (uint32_t)(c * HW)] = acc[c] * 0.03125f;  // /32
}

extern "C" void kernel_launch(void* const* d_in, const int* in_sizes, int n_in,
                              void* d_out, int out_size, void* d_ws, size_t ws_size,
                              hipStream_t stream) {
  const float* logits = (const float*)d_in[0];
  const float* stdv   = (const float*)d_in[1];
  float* out = (float*)d_out;

  // Per-sample folded keys: fold_in(key(42), s) = threefry2x32(key=(0,42), msg=(0,s))
  SampleKeys keys;
  for (int s = 0; s < NSAMP; ++s) {
    uint32_t o0, o1;
    tf2x32(0u, 42u, 0u, (uint32_t)s, o0, o1);
    keys.k0[s] = o0;
    keys.k1[s] = o1;
  }

  dim3 grid(NPIX / 256), block(256);
  mcsm<<<grid, block, 0, stream>>>(logits, stdv, out, keys);
}

// Round 4
// 2456.024 us; speedup vs baseline: 1.1186x; 1.1186x over previous
//
#include <hip/hip_runtime.h>
#include <stdint.h>

#define NB 8
#define NC 19
#define NH 512
#define NW 512
#define HW (NH * NW)        // 262144
#define CHW (NC * HW)       // 4980736
#define NPIX (NB * HW)      // 2097152
#define NSAMP 32

struct SampleKeys { uint32_t k0[NSAMP]; uint32_t k1[NSAMP]; };

// Threefry-2x32, 20 rounds, exactly JAX's threefry2x32 primitive.
__host__ __device__ inline void tf2x32(uint32_t k0, uint32_t k1,
                                       uint32_t c0, uint32_t c1,
                                       uint32_t &o0, uint32_t &o1) {
  const uint32_t ks2 = k0 ^ k1 ^ 0x1BD11BDAu;
  uint32_t x0 = c0 + k0;
  uint32_t x1 = c1 + k1;
#define TFR(r) do { x0 += x1; x1 = (x1 << (r)) | (x1 >> (32 - (r))); x1 ^= x0; } while (0)
  TFR(13); TFR(15); TFR(26); TFR(6);
  x0 += k1; x1 += ks2 + 1u;
  TFR(17); TFR(29); TFR(16); TFR(24);
  x0 += ks2; x1 += k0 + 2u;
  TFR(13); TFR(15); TFR(26); TFR(6);
  x0 += k0; x1 += k1 + 3u;
  TFR(17); TFR(29); TFR(16); TFR(24);
  x0 += k1; x1 += ks2 + 4u;
  TFR(13); TFR(15); TFR(26); TFR(6);
  x0 += ks2; x1 += k0 + 5u;
#undef TFR
  o0 = x0; o1 = x1;
}

// Device-side hash body given pre-added counter word (x1 init = c1 + k1 done
// by caller as base + scalar(c*HW + k1)).
__device__ __forceinline__ void tf2x32_pre(uint32_t k0, uint32_t k1, uint32_t ks2,
                                           uint32_t x1, uint32_t &o0, uint32_t &o1) {
  uint32_t x0 = k0;  // c0 = 0, so x0 = 0 + k0 (scalar)
#define TFR(r) do { x0 += x1; x1 = (x1 << (r)) | (x1 >> (32 - (r))); x1 ^= x0; } while (0)
  TFR(13); TFR(15); TFR(26); TFR(6);
  x0 += k1; x1 += ks2 + 1u;
  TFR(17); TFR(29); TFR(16); TFR(24);
  x0 += ks2; x1 += k0 + 2u;
  TFR(13); TFR(15); TFR(26); TFR(6);
  x0 += k0; x1 += k1 + 3u;
  TFR(17); TFR(29); TFR(16); TFR(24);
  x0 += k1; x1 += ks2 + 4u;
  TFR(13); TFR(15); TFR(26); TFR(6);
  x0 += ks2; x1 += k0 + 5u;
#undef TFR
  o0 = x0; o1 = x1;
}

// bits -> p*u where eps = sqrt(2)*erfinv(u) = sqrt(2)*(p*u). The sqrt(2) is
// folded into the caller's sd3[] scale. RNG bit-stream frozen (verified r1-3).
__device__ __forceinline__ float normal_pu(uint32_t bits) {
  const float LO = -0.99999994039535522461f;  // nextafter(-1.f, 0.f)
  float f = __uint_as_float((bits >> 9) | 0x3F800000u) - 1.0f;  // [0,1)
  float u = fmaf(f, 2.0f, LO);                 // min is exactly LO: clamp dropped
  float W2 = __builtin_amdgcn_logf(fmaf(-u, u, 1.0f));   // log2(1-u^2)
  float wl = fmaf(W2, -0.69314718056f, -2.5f);           // w - 2.5, w = -ln(1-u^2)
  float p = 2.81022636e-08f;
  p = fmaf(p, wl, 3.43273939e-07f);
  p = fmaf(p, wl, -3.5233877e-06f);
  p = fmaf(p, wl, -4.39150654e-06f);
  p = fmaf(p, wl, 0.00021858087f);
  p = fmaf(p, wl, -0.00125372503f);
  p = fmaf(p, wl, -0.00417768164f);
  p = fmaf(p, wl, 0.246640727f);
  p = fmaf(p, wl, 1.50140941f);
  if (__builtin_expect(__any(wl >= 2.5f), 0)) {   // w >= 5, p ~ 0.34%/lane
    float w = wl + 2.5f;
    float wh = __builtin_amdgcn_sqrtf(w) - 3.0f;
    float q = -0.000200214257f;
    q = fmaf(q, wh, 0.000100950558f);
    q = fmaf(q, wh, 0.00134934322f);
    q = fmaf(q, wh, -0.00367342844f);
    q = fmaf(q, wh, 0.00573950773f);
    q = fmaf(q, wh, -0.0076224613f);
    q = fmaf(q, wh, 0.00943887047f);
    q = fmaf(q, wh, 1.00167406f);
    q = fmaf(q, wh, 2.83297682f);
    p = (wl < 2.5f) ? p : q;
  }
  return p * u;
}

// waves_per_eu(2,3): cap occupancy chase at 3 waves/SIMD so the pre-RA
// scheduler keeps the 19 independent threefry chains interleaved (ILP)
// instead of serializing them to fit a small register budget. Rounds 2-3
// showed the allocator picking 64-72 VGPRs and serializing -> ~53% issue
// efficiency at identical 3.22 ms regardless of occupancy/spills.
__global__ __launch_bounds__(256)
__attribute__((amdgpu_waves_per_eu(2, 3)))
void mcsm(const float* __restrict__ logits,
          const float* __restrict__ stdv,
          float* __restrict__ out,
          SampleKeys keys) {
  uint32_t p = blockIdx.x * 256u + threadIdx.x;  // pixel id in [0, NPIX)
  uint32_t b = p >> 18;                          // / HW
  uint32_t rem = p & (HW - 1u);                  // h*W + w
  uint32_t base = b * (uint32_t)CHW + rem;       // flat index at c=0

  const float SQRT2_LOG2E = 2.03986953234f;      // sqrt(2) * log2(e)
  const float LOG2E = 1.44269504089f;

  float lg2[NC], sd3[NC], acc[NC];
#pragma unroll
  for (int c = 0; c < NC; ++c) {
    lg2[c] = logits[base + (uint32_t)(c * HW)] * LOG2E;
    sd3[c] = stdv[base + (uint32_t)(c * HW)] * SQRT2_LOG2E;
    acc[c] = 0.0f;
  }

#pragma unroll 1
  for (int s = 0; s < NSAMP; ++s) {
    const uint32_t k0 = keys.k0[s], k1 = keys.k1[s];
    const uint32_t ks2 = k0 ^ k1 ^ 0x1BD11BDAu;
    float ts[NC];
    float sum = 0.0f;
    // softmax(x) = exp2(x*log2e - ...) ; no max-subtraction (|x| <= ~12).
#pragma unroll
    for (int c = 0; c < NC; ++c) {
      uint32_t o0, o1;
      // (c*HW + k1) is wave-uniform -> SALU; one VALU add for the counter.
      tf2x32_pre(k0, k1, ks2, base + ((uint32_t)(c * HW) + k1), o0, o1);
      float pu = normal_pu(o0 ^ o1);           // partitionable: xor of halves
      float t = __builtin_amdgcn_exp2f(fmaf(pu, sd3[c], lg2[c]));
      ts[c] = t;
      sum += t;
    }
    float rs = __builtin_amdgcn_rcpf(sum);
#pragma unroll
    for (int c = 0; c < NC; ++c) acc[c] = fmaf(ts[c], rs, acc[c]);
  }

#pragma unroll
  for (int c = 0; c < NC; ++c)
    out[base + (uint32_t)(c * HW)] = acc[c] * 0.03125f;  // /32
}

extern "C" void kernel_launch(void* const* d_in, const int* in_sizes, int n_in,
                              void* d_out, int out_size, void* d_ws, size_t ws_size,
                              hipStream_t stream) {
  const float* logits = (const float*)d_in[0];
  const float* stdv   = (const float*)d_in[1];
  float* out = (float*)d_out;

  // Per-sample folded keys: fold_in(key(42), s) = threefry2x32(key=(0,42), msg=(0,s))
  SampleKeys keys;
  for (int s = 0; s < NSAMP; ++s) {
    uint32_t o0, o1;
    tf2x32(0u, 42u, 0u, (uint32_t)s, o0, o1);
    keys.k0[s] = o0;
    keys.k1[s] = o1;
  }

  dim3 grid(NPIX / 256), block(256);
  mcsm<<<grid, block, 0, stream>>>(logits, stdv, out, keys);
}

// Round 5
// 2435.215 us; speedup vs baseline: 1.1282x; 1.0085x over previous
//
#include <hip/hip_runtime.h>
#include <stdint.h>

#define NB 8
#define NC 19
#define NH 512
#define NW 512
#define HW (NH * NW)        // 262144
#define CHW (NC * HW)       // 4980736
#define NPIX (NB * HW)      // 2097152
#define NSAMP 32

struct SampleKeys { uint32_t k0[NSAMP]; uint32_t k1[NSAMP]; };

// Threefry-2x32, 20 rounds, exactly JAX's threefry2x32 primitive.
__host__ __device__ inline void tf2x32(uint32_t k0, uint32_t k1,
                                       uint32_t c0, uint32_t c1,
                                       uint32_t &o0, uint32_t &o1) {
  const uint32_t ks2 = k0 ^ k1 ^ 0x1BD11BDAu;
  uint32_t x0 = c0 + k0;
  uint32_t x1 = c1 + k1;
#define TFR(r) do { x0 += x1; x1 = (x1 << (r)) | (x1 >> (32 - (r))); x1 ^= x0; } while (0)
  TFR(13); TFR(15); TFR(26); TFR(6);
  x0 += k1; x1 += ks2 + 1u;
  TFR(17); TFR(29); TFR(16); TFR(24);
  x0 += ks2; x1 += k0 + 2u;
  TFR(13); TFR(15); TFR(26); TFR(6);
  x0 += k0; x1 += k1 + 3u;
  TFR(17); TFR(29); TFR(16); TFR(24);
  x0 += k1; x1 += ks2 + 4u;
  TFR(13); TFR(15); TFR(26); TFR(6);
  x0 += ks2; x1 += k0 + 5u;
#undef TFR
  o0 = x0; o1 = x1;
}

// Device-side hash body given pre-added counter word (x1 init = c1 + k1 done
// by caller as base + scalar(c*HW + k1)).
__device__ __forceinline__ void tf2x32_pre(uint32_t k0, uint32_t k1, uint32_t ks2,
                                           uint32_t x1, uint32_t &o0, uint32_t &o1) {
  uint32_t x0 = k0;  // c0 = 0, so x0 = 0 + k0 (scalar)
#define TFR(r) do { x0 += x1; x1 = (x1 << (r)) | (x1 >> (32 - (r))); x1 ^= x0; } while (0)
  TFR(13); TFR(15); TFR(26); TFR(6);
  x0 += k1; x1 += ks2 + 1u;
  TFR(17); TFR(29); TFR(16); TFR(24);
  x0 += ks2; x1 += k0 + 2u;
  TFR(13); TFR(15); TFR(26); TFR(6);
  x0 += k0; x1 += k1 + 3u;
  TFR(17); TFR(29); TFR(16); TFR(24);
  x0 += k1; x1 += ks2 + 4u;
  TFR(13); TFR(15); TFR(26); TFR(6);
  x0 += ks2; x1 += k0 + 5u;
#undef TFR
  o0 = x0; o1 = x1;
}

// bits -> p*u where eps = sqrt(2)*erfinv(u) = sqrt(2)*(p*u). The sqrt(2) is
// folded into the caller's sd3[] scale. RNG bit-stream frozen (verified r1-4).
__device__ __forceinline__ float normal_pu(uint32_t bits) {
  const float LO = -0.99999994039535522461f;  // nextafter(-1.f, 0.f)
  float f = __uint_as_float((bits >> 9) | 0x3F800000u) - 1.0f;  // [0,1)
  float u = fmaf(f, 2.0f, LO);                 // min is exactly LO: clamp dropped
  float W2 = __builtin_amdgcn_logf(fmaf(-u, u, 1.0f));   // log2(1-u^2)
  float wl = fmaf(W2, -0.69314718056f, -2.5f);           // w - 2.5, w = -ln(1-u^2)
  float p = 2.81022636e-08f;
  p = fmaf(p, wl, 3.43273939e-07f);
  p = fmaf(p, wl, -3.5233877e-06f);
  p = fmaf(p, wl, -4.39150654e-06f);
  p = fmaf(p, wl, 0.00021858087f);
  p = fmaf(p, wl, -0.00125372503f);
  p = fmaf(p, wl, -0.00417768164f);
  p = fmaf(p, wl, 0.246640727f);
  p = fmaf(p, wl, 1.50140941f);
  if (__builtin_expect(__any(wl >= 2.5f), 0)) {   // w >= 5, p ~ 0.34%/lane
    float w = wl + 2.5f;
    float wh = __builtin_amdgcn_sqrtf(w) - 3.0f;
    float q = -0.000200214257f;
    q = fmaf(q, wh, 0.000100950558f);
    q = fmaf(q, wh, 0.00134934322f);
    q = fmaf(q, wh, -0.00367342844f);
    q = fmaf(q, wh, 0.00573950773f);
    q = fmaf(q, wh, -0.0076224613f);
    q = fmaf(q, wh, 0.00943887047f);
    q = fmaf(q, wh, 1.00167406f);
    q = fmaf(q, wh, 2.83297682f);
    p = (wl < 2.5f) ? p : q;
  }
  return p * u;
}

// waves_per_eu(4,4): EXACT occupancy target. min=4 -> 128-VGPR budget (live
// state ~76 floats + temps fits); max=4 -> allocator gains nothing by
// shrinking below 128, so it stops serializing chains to chase 8 waves
// (rounds 1-2 failure mode). Round 4 measured ~55% VALU issue efficiency at
// 2.76 waves/SIMD (self-imposed cap) -> latency-bound, need more waves AND
// full register budget.
__global__ __launch_bounds__(256)
__attribute__((amdgpu_waves_per_eu(4, 4)))
void mcsm(const float* __restrict__ logits,
          const float* __restrict__ stdv,
          float* __restrict__ out,
          SampleKeys keys) {
  uint32_t p = blockIdx.x * 256u + threadIdx.x;  // pixel id in [0, NPIX)
  uint32_t b = p >> 18;                          // / HW
  uint32_t rem = p & (HW - 1u);                  // h*W + w
  uint32_t base = b * (uint32_t)CHW + rem;       // flat index at c=0

  const float SQRT2_LOG2E = 2.03986953234f;      // sqrt(2) * log2(e)
  const float LOG2E = 1.44269504089f;

  float lg2[NC], sd3[NC], acc[NC];
#pragma unroll
  for (int c = 0; c < NC; ++c) {
    lg2[c] = logits[base + (uint32_t)(c * HW)] * LOG2E;
    sd3[c] = stdv[base + (uint32_t)(c * HW)] * SQRT2_LOG2E;
    acc[c] = 0.0f;
  }

#pragma unroll 1
  for (int s = 0; s < NSAMP; ++s) {
    const uint32_t k0 = keys.k0[s], k1 = keys.k1[s];
    const uint32_t ks2 = k0 ^ k1 ^ 0x1BD11BDAu;
    float ts[NC];
    float sum = 0.0f;
    // softmax(x) = exp2(x*log2e - ...) ; no max-subtraction (|x| <= ~12).
#pragma unroll
    for (int c = 0; c < NC; ++c) {
      uint32_t o0, o1;
      // (c*HW + k1) is wave-uniform -> SALU; one VALU add for the counter.
      tf2x32_pre(k0, k1, ks2, base + ((uint32_t)(c * HW) + k1), o0, o1);
      float pu = normal_pu(o0 ^ o1);           // partitionable: xor of halves
      float t = __builtin_amdgcn_exp2f(fmaf(pu, sd3[c], lg2[c]));
      ts[c] = t;
      sum += t;
    }
    float rs = __builtin_amdgcn_rcpf(sum);
#pragma unroll
    for (int c = 0; c < NC; ++c) acc[c] = fmaf(ts[c], rs, acc[c]);
  }

#pragma unroll
  for (int c = 0; c < NC; ++c)
    out[base + (uint32_t)(c * HW)] = acc[c] * 0.03125f;  // /32
}

extern "C" void kernel_launch(void* const* d_in, const int* in_sizes, int n_in,
                              void* d_out, int out_size, void* d_ws, size_t ws_size,
                              hipStream_t stream) {
  const float* logits = (const float*)d_in[0];
  const float* stdv   = (const float*)d_in[1];
  float* out = (float*)d_out;

  // Per-sample folded keys: fold_in(key(42), s) = threefry2x32(key=(0,42), msg=(0,s))
  SampleKeys keys;
  for (int s = 0; s < NSAMP; ++s) {
    uint32_t o0, o1;
    tf2x32(0u, 42u, 0u, (uint32_t)s, o0, o1);
    keys.k0[s] = o0;
    keys.k1[s] = o1;
  }

  dim3 grid(NPIX / 256), block(256);
  mcsm<<<grid, block, 0, stream>>>(logits, stdv, out, keys);
}

// Round 6
// 2426.760 us; speedup vs baseline: 1.1321x; 1.0035x over previous
//
#include <hip/hip_runtime.h>
#include <stdint.h>

#define NB 8
#define NC 19
#define NH 512
#define NW 512
#define HW (NH * NW)        // 262144
#define CHW (NC * HW)       // 4980736
#define NPIX (NB * HW)      // 2097152
#define NSAMP 32

struct SampleKeys { uint32_t k0[NSAMP]; uint32_t k1[NSAMP]; };

// Threefry-2x32, 20 rounds, exactly JAX's threefry2x32 primitive.
__host__ __device__ inline void tf2x32(uint32_t k0, uint32_t k1,
                                       uint32_t c0, uint32_t c1,
                                       uint32_t &o0, uint32_t &o1) {
  const uint32_t ks2 = k0 ^ k1 ^ 0x1BD11BDAu;
  uint32_t x0 = c0 + k0;
  uint32_t x1 = c1 + k1;
#define TFR(r) do { x0 += x1; x1 = (x1 << (r)) | (x1 >> (32 - (r))); x1 ^= x0; } while (0)
  TFR(13); TFR(15); TFR(26); TFR(6);
  x0 += k1; x1 += ks2 + 1u;
  TFR(17); TFR(29); TFR(16); TFR(24);
  x0 += ks2; x1 += k0 + 2u;
  TFR(13); TFR(15); TFR(26); TFR(6);
  x0 += k0; x1 += k1 + 3u;
  TFR(17); TFR(29); TFR(16); TFR(24);
  x0 += k1; x1 += ks2 + 4u;
  TFR(13); TFR(15); TFR(26); TFR(6);
  x0 += ks2; x1 += k0 + 5u;
#undef TFR
  o0 = x0; o1 = x1;
}

// Device-side hash body; x1 pre-added by caller (c1 + k1), c0 = 0.
__device__ __forceinline__ void tf2x32_pre(uint32_t k0, uint32_t k1, uint32_t ks2,
                                           uint32_t x1, uint32_t &o0, uint32_t &o1) {
  uint32_t x0 = k0;
#define TFR(r) do { x0 += x1; x1 = (x1 << (r)) | (x1 >> (32 - (r))); x1 ^= x0; } while (0)
  TFR(13); TFR(15); TFR(26); TFR(6);
  x0 += k1; x1 += ks2 + 1u;
  TFR(17); TFR(29); TFR(16); TFR(24);
  x0 += ks2; x1 += k0 + 2u;
  TFR(13); TFR(15); TFR(26); TFR(6);
  x0 += k0; x1 += k1 + 3u;
  TFR(17); TFR(29); TFR(16); TFR(24);
  x0 += k1; x1 += ks2 + 4u;
  TFR(13); TFR(15); TFR(26); TFR(6);
  x0 += ks2; x1 += k0 + 5u;
#undef TFR
  o0 = x0; o1 = x1;
}

// bits -> p*u where eps = sqrt(2)*erfinv(u) = sqrt(2)*(p*u); sqrt(2) folded
// into sd3 scale. RNG bit-stream frozen (verified rounds 1-5).
__device__ __forceinline__ float normal_pu(uint32_t bits) {
  const float LO = -0.99999994039535522461f;  // nextafter(-1.f, 0.f)
  float f = __uint_as_float((bits >> 9) | 0x3F800000u) - 1.0f;  // [0,1)
  float u = fmaf(f, 2.0f, LO);
  float W2 = __builtin_amdgcn_logf(fmaf(-u, u, 1.0f));   // log2(1-u^2)
  float wl = fmaf(W2, -0.69314718056f, -2.5f);           // w - 2.5
  float p = 2.81022636e-08f;
  p = fmaf(p, wl, 3.43273939e-07f);
  p = fmaf(p, wl, -3.5233877e-06f);
  p = fmaf(p, wl, -4.39150654e-06f);
  p = fmaf(p, wl, 0.00021858087f);
  p = fmaf(p, wl, -0.00125372503f);
  p = fmaf(p, wl, -0.00417768164f);
  p = fmaf(p, wl, 0.246640727f);
  p = fmaf(p, wl, 1.50140941f);
  if (__builtin_expect(__any(wl >= 2.5f), 0)) {   // w >= 5, ~0.34%/lane
    float w = wl + 2.5f;
    float wh = __builtin_amdgcn_sqrtf(w) - 3.0f;
    float q = -0.000200214257f;
    q = fmaf(q, wh, 0.000100950558f);
    q = fmaf(q, wh, 0.00134934322f);
    q = fmaf(q, wh, -0.00367342844f);
    q = fmaf(q, wh, 0.00573950773f);
    q = fmaf(q, wh, -0.0076224613f);
    q = fmaf(q, wh, 0.00943887047f);
    q = fmaf(q, wh, 1.00167406f);
    q = fmaf(q, wh, 2.83297682f);
    p = (wl < 2.5f) ? p : q;
  }
  return p * u;
}

// Structural register-pressure fix (rounds 2-5: allocator refuses >72 VGPRs;
// live state 76+ floats -> either spills or serialized hash chains, both
// ~52% issue efficiency). lg2/sd3 (38 regs) move to LDS as per-thread
// PRIVATE storage: lsd[c][tid], no cross-thread sharing, no barriers.
// Address = tid*8 + compile-time offset c*2048 -> zero address math,
// conflict-free stride-2 bank pattern. 38 KB/block -> 4 blocks/CU (50% occ).
__global__ __launch_bounds__(256, 4)
void mcsm(const float* __restrict__ logits,
          const float* __restrict__ stdv,
          float* __restrict__ out,
          SampleKeys keys) {
  __shared__ float2 lsd[NC][256];

  const uint32_t tid = threadIdx.x;
  uint32_t p = blockIdx.x * 256u + tid;          // pixel id in [0, NPIX)
  uint32_t b = p >> 18;                          // / HW
  uint32_t rem = p & (HW - 1u);                  // h*W + w
  uint32_t base = b * (uint32_t)CHW + rem;       // flat index at c=0

  const float SQRT2_LOG2E = 2.03986953234f;      // sqrt(2) * log2(e)
  const float LOG2E = 1.44269504089f;

  float acc[NC];
#pragma unroll
  for (int c = 0; c < NC; ++c) {
    float lg2 = logits[base + (uint32_t)(c * HW)] * LOG2E;
    float sd3 = stdv[base + (uint32_t)(c * HW)] * SQRT2_LOG2E;
    lsd[c][tid] = make_float2(lg2, sd3);
    acc[c] = 0.0f;
  }

#pragma unroll 1
  for (int s = 0; s < NSAMP; ++s) {
    const uint32_t k0 = keys.k0[s], k1 = keys.k1[s];
    const uint32_t ks2 = k0 ^ k1 ^ 0x1BD11BDAu;
    float ts[NC];
    float sum = 0.0f;
#pragma unroll
    for (int c = 0; c < NC; ++c) {
      uint32_t o0, o1;
      // (c*HW + k1) is wave-uniform -> SALU; one VALU add for the counter.
      tf2x32_pre(k0, k1, ks2, base + ((uint32_t)(c * HW) + k1), o0, o1);
      float pu = normal_pu(o0 ^ o1);           // partitionable: xor of halves
      float2 v = lsd[c][tid];                  // ds_read_b64, imm offset
      float t = __builtin_amdgcn_exp2f(fmaf(pu, v.y, v.x));
      ts[c] = t;
      sum += t;
    }
    float rs = __builtin_amdgcn_rcpf(sum);
#pragma unroll
    for (int c = 0; c < NC; ++c) acc[c] = fmaf(ts[c], rs, acc[c]);
  }

#pragma unroll
  for (int c = 0; c < NC; ++c)
    out[base + (uint32_t)(c * HW)] = acc[c] * 0.03125f;  // /32
}

extern "C" void kernel_launch(void* const* d_in, const int* in_sizes, int n_in,
                              void* d_out, int out_size, void* d_ws, size_t ws_size,
                              hipStream_t stream) {
  const float* logits = (const float*)d_in[0];
  const float* stdv   = (const float*)d_in[1];
  float* out = (float*)d_out;

  // Per-sample folded keys: fold_in(key(42), s) = threefry2x32(key=(0,42), msg=(0,s))
  SampleKeys keys;
  for (int s = 0; s < NSAMP; ++s) {
    uint32_t o0, o1;
    tf2x32(0u, 42u, 0u, (uint32_t)s, o0, o1);
    keys.k0[s] = o0;
    keys.k1[s] = o1;
  }

  dim3 grid(NPIX / 256), block(256);
  mcsm<<<grid, block, 0, stream>>>(logits, stdv, out, keys);
}

// Round 7
// 2371.280 us; speedup vs baseline: 1.1586x; 1.0234x over previous
//
#include <hip/hip_runtime.h>
#include <stdint.h>

#define NB 8
#define NC 19
#define NH 512
#define NW 512
#define HW (NH * NW)        // 262144
#define CHW (NC * HW)       // 4980736
#define NPIX (NB * HW)      // 2097152
#define NSAMP 32

struct SampleKeys { uint32_t k0[NSAMP]; uint32_t k1[NSAMP]; };

// Threefry-2x32, 20 rounds, exactly JAX's threefry2x32 primitive.
__host__ __device__ inline void tf2x32(uint32_t k0, uint32_t k1,
                                       uint32_t c0, uint32_t c1,
                                       uint32_t &o0, uint32_t &o1) {
  const uint32_t ks2 = k0 ^ k1 ^ 0x1BD11BDAu;
  uint32_t x0 = c0 + k0;
  uint32_t x1 = c1 + k1;
#define TFR(r) do { x0 += x1; x1 = (x1 << (r)) | (x1 >> (32 - (r))); x1 ^= x0; } while (0)
  TFR(13); TFR(15); TFR(26); TFR(6);
  x0 += k1; x1 += ks2 + 1u;
  TFR(17); TFR(29); TFR(16); TFR(24);
  x0 += ks2; x1 += k0 + 2u;
  TFR(13); TFR(15); TFR(26); TFR(6);
  x0 += k0; x1 += k1 + 3u;
  TFR(17); TFR(29); TFR(16); TFR(24);
  x0 += k1; x1 += ks2 + 4u;
  TFR(13); TFR(15); TFR(26); TFR(6);
  x0 += ks2; x1 += k0 + 5u;
#undef TFR
  o0 = x0; o1 = x1;
}

// Device-side hash body; x1 pre-added by caller (c1 + k1), c0 = 0.
__device__ __forceinline__ void tf2x32_pre(uint32_t k0, uint32_t k1, uint32_t ks2,
                                           uint32_t x1, uint32_t &o0, uint32_t &o1) {
  uint32_t x0 = k0;
#define TFR(r) do { x0 += x1; x1 = (x1 << (r)) | (x1 >> (32 - (r))); x1 ^= x0; } while (0)
  TFR(13); TFR(15); TFR(26); TFR(6);
  x0 += k1; x1 += ks2 + 1u;
  TFR(17); TFR(29); TFR(16); TFR(24);
  x0 += ks2; x1 += k0 + 2u;
  TFR(13); TFR(15); TFR(26); TFR(6);
  x0 += k0; x1 += k1 + 3u;
  TFR(17); TFR(29); TFR(16); TFR(24);
  x0 += k1; x1 += ks2 + 4u;
  TFR(13); TFR(15); TFR(26); TFR(6);
  x0 += ks2; x1 += k0 + 5u;
#undef TFR
  o0 = x0; o1 = x1;
}

// bits -> p*u where eps = sqrt(2)*erfinv(u) = sqrt(2)*(p*u); sqrt(2) folded
// into sd3 scale. RNG bit-stream frozen (verified rounds 1-6).
// Golf: mantissa pack via one v_alignbit (0x3F800000|(bits>>9)); low-branch
// poly truncated 9->5 terms (trunc err <=1e-3 rel at |u|->0.9966, -> output
// err ~1e-4 vs 13.8e-3 margin). High branch (guarded, ~0.3% of lanes) full.
__device__ __forceinline__ float normal_pu(uint32_t bits) {
  const float LO = -0.99999994039535522461f;  // nextafter(-1.f, 0.f)
  float f = __uint_as_float(__builtin_amdgcn_alignbit(0x7Fu, bits, 9u)) - 1.0f;
  float u = fmaf(f, 2.0f, LO);
  float W2 = __builtin_amdgcn_logf(fmaf(-u, u, 1.0f));   // log2(1-u^2)
  float wl = fmaf(W2, -0.69314718056f, -2.5f);           // w - 2.5
  float p = 0.00021858087f;
  p = fmaf(p, wl, -0.00125372503f);
  p = fmaf(p, wl, -0.00417768164f);
  p = fmaf(p, wl, 0.246640727f);
  p = fmaf(p, wl, 1.50140941f);
  if (__builtin_expect(__any(wl >= 2.5f), 0)) {   // w >= 5, ~0.34%/lane
    float w = wl + 2.5f;
    float wh = __builtin_amdgcn_sqrtf(w) - 3.0f;
    float q = -0.000200214257f;
    q = fmaf(q, wh, 0.000100950558f);
    q = fmaf(q, wh, 0.00134934322f);
    q = fmaf(q, wh, -0.00367342844f);
    q = fmaf(q, wh, 0.00573950773f);
    q = fmaf(q, wh, -0.0076224613f);
    q = fmaf(q, wh, 0.00943887047f);
    q = fmaf(q, wh, 1.00167406f);
    q = fmaf(q, wh, 2.83297682f);
    p = (wl < 2.5f) ? p : q;
  }
  return p * u;
}

// Structure frozen at r6 (knob-invariance proven r3-r6: time tracks op count
// only). lg2/sd3 in LDS as per-thread private slots, no barriers.
__global__ __launch_bounds__(256, 4)
void mcsm(const float* __restrict__ logits,
          const float* __restrict__ stdv,
          float* __restrict__ out,
          SampleKeys keys) {
  __shared__ float2 lsd[NC][256];

  const uint32_t tid = threadIdx.x;
  uint32_t p = blockIdx.x * 256u + tid;          // pixel id in [0, NPIX)
  uint32_t b = p >> 18;                          // / HW
  uint32_t rem = p & (HW - 1u);                  // h*W + w
  uint32_t base = b * (uint32_t)CHW + rem;       // flat index at c=0

  const float SQRT2_LOG2E = 2.03986953234f;      // sqrt(2) * log2(e)
  const float LOG2E = 1.44269504089f;

  float acc[NC];
#pragma unroll
  for (int c = 0; c < NC; ++c) {
    float lg2 = logits[base + (uint32_t)(c * HW)] * LOG2E;
    float sd3 = stdv[base + (uint32_t)(c * HW)] * SQRT2_LOG2E;
    lsd[c][tid] = make_float2(lg2, sd3);
    acc[c] = 0.0f;
  }

#pragma unroll 1
  for (int s = 0; s < NSAMP; ++s) {
    const uint32_t k0 = keys.k0[s], k1 = keys.k1[s];
    const uint32_t ks2 = k0 ^ k1 ^ 0x1BD11BDAu;
    float ts[NC];
    float sum = 0.0f;
#pragma unroll
    for (int c = 0; c < NC; ++c) {
      uint32_t o0, o1;
      // (c*HW + k1) is wave-uniform -> SALU; one VALU add for the counter.
      tf2x32_pre(k0, k1, ks2, base + ((uint32_t)(c * HW) + k1), o0, o1);
      float pu = normal_pu(o0 ^ o1);           // partitionable: xor of halves
      float2 v = lsd[c][tid];                  // ds_read_b64, imm offset
      float t = __builtin_amdgcn_exp2f(fmaf(pu, v.y, v.x));
      ts[c] = t;
      sum += t;
    }
    float rs = __builtin_amdgcn_rcpf(sum);
#pragma unroll
    for (int c = 0; c < NC; ++c) acc[c] = fmaf(ts[c], rs, acc[c]);
  }

#pragma unroll
  for (int c = 0; c < NC; ++c)
    out[base + (uint32_t)(c * HW)] = acc[c] * 0.03125f;  // /32
}

extern "C" void kernel_launch(void* const* d_in, const int* in_sizes, int n_in,
                              void* d_out, int out_size, void* d_ws, size_t ws_size,
                              hipStream_t stream) {
  const float* logits = (const float*)d_in[0];
  const float* stdv   = (const float*)d_in[1];
  float* out = (float*)d_out;

  // Per-sample folded keys: fold_in(key(42), s) = threefry2x32(key=(0,42), msg=(0,s))
  SampleKeys keys;
  for (int s = 0; s < NSAMP; ++s) {
    uint32_t o0, o1;
    tf2x32(0u, 42u, 0u, (uint32_t)s, o0, o1);
    keys.k0[s] = o0;
    keys.k1[s] = o1;
  }

  dim3 grid(NPIX / 256), block(256);
  mcsm<<<grid, block, 0, stream>>>(logits, stdv, out, keys);
}